// Round 6
// baseline (837.449 us; speedup 1.0000x reference)
//
#include <hip/hip_runtime.h>
#include <math.h>

#define SD 7
#define HID 64
#define NITER 10

typedef float f16s __attribute__((ext_vector_type(16)));
typedef float f8s  __attribute__((ext_vector_type(8)));

#define REP4(M)  M(0) M(1) M(2) M(3)
#define REP7(M)  M(0) M(1) M(2) M(3) M(4) M(5) M(6)
#define REP15(M) M(1) M(2) M(3) M(4) M(5) M(6) M(7) M(8) M(9) M(10) M(11) M(12) M(13) M(14) M(15)
#define REP16(M) M(0) M(1) M(2) M(3) M(4) M(5) M(6) M(7) M(8) M(9) M(10) M(11) M(12) M(13) M(14) M(15)
#define AP16(M, ...) M(0, __VA_ARGS__) M(1, __VA_ARGS__) M(2, __VA_ARGS__) M(3, __VA_ARGS__) \
    M(4, __VA_ARGS__) M(5, __VA_ARGS__) M(6, __VA_ARGS__) M(7, __VA_ARGS__) \
    M(8, __VA_ARGS__) M(9, __VA_ARGS__) M(10, __VA_ARGS__) M(11, __VA_ARGS__) \
    M(12, __VA_ARGS__) M(13, __VA_ARGS__) M(14, __VA_ARGS__) M(15, __VA_ARGS__)

// 64 uniform floats -> SGPRs via scalar cache. volatile => never hoisted/CSE'd.
#define SLOAD4(d0, d1, d2, d3, p, o0, o1, o2, o3) \
    asm volatile("s_load_dwordx16 %0, %4, %5\n\t" \
                 "s_load_dwordx16 %1, %4, %6\n\t" \
                 "s_load_dwordx16 %2, %4, %7\n\t" \
                 "s_load_dwordx16 %3, %4, %8\n\t" \
                 "s_waitcnt lgkmcnt(0)" \
                 : "=&s"(d0), "=&s"(d1), "=&s"(d2), "=&s"(d3) \
                 : "s"(p), "i"(o0), "i"(o1), "i"(o2), "i"(o3));

#define SLOAD2P(d0, d1, pa, pb, oa, ob_) \
    asm volatile("s_load_dwordx16 %0, %2, %4\n\t" \
                 "s_load_dwordx16 %1, %3, %5\n\t" \
                 "s_waitcnt lgkmcnt(0)" \
                 : "=&s"(d0), "=&s"(d1) \
                 : "s"(pa), "s"(pb), "i"(oa), "i"(ob_));

#define SLOADX8(d0, p) \
    asm volatile("s_load_dwordx8 %0, %1, 0\n\t" \
                 "s_waitcnt lgkmcnt(0)" \
                 : "=&s"(d0) : "s"(p));

// one fma row element: arr[base+e] = fma(m, W[e], arr[base+e])
#define FMAE(e, arr, base, m, W) (arr)[(base)+(e)] = fmaf((m), (W)[(e)], (arr)[(base)+(e)]);
#define FMAROW(arr, m, wa, wb, wc, wd) \
    AP16(FMAE, arr, 0,  m, wa) AP16(FMAE, arr, 16, m, wb) \
    AP16(FMAE, arr, 32, m, wc) AP16(FMAE, arr, 48, m, wd)

__global__ __launch_bounds__(256) __attribute__((amdgpu_waves_per_eu(3)))
void strange_loop_kernel(const float* __restrict__ s7,
                         const float* __restrict__ w0,
                         const float* __restrict__ b0,
                         const float* __restrict__ lns,
                         const float* __restrict__ lnb,
                         const float* __restrict__ ow,
                         const float* __restrict__ ob,
                         float* __restrict__ out_mu,
                         float* __restrict__ out_cv,
                         int Bn)
{
    int row = blockIdx.x * blockDim.x + threadIdx.x;
    if (row >= Bn) row = Bn - 1;   // clamp: uniform control flow, dup write benign

    float s[SD];
#define LD_S(k) s[k] = s7[(size_t)row * SD + (k)];
    REP7(LD_S)

    f8s obv;
    SLOADX8(obv, ob)

    float mu[SD];
#define INITMU(i) mu[i] = 0.37796447300922720f;   // 1/sqrt(7)
    REP7(INITMU)
    float conv = 0.0f;

#pragma unroll 1
    for (int it = 0; it < NITER; ++it) {
        // ---- fc0: xe = b0, then + s-rows (ctx), then + mu-rows ----
        // (same accumulation order as the passing round-4 kernel: b0, s0..s6, mu0..mu6)
        float xe[HID];
        {
            f16s ba, bb, bc, bd;
            SLOAD4(ba, bb, bc, bd, b0, 0, 64, 128, 192)
#define B0E(e, base, W) xe[(base)+(e)] = (W)[(e)];
            AP16(B0E, 0, ba) AP16(B0E, 16, bb) AP16(B0E, 32, bc) AP16(B0E, 48, bd)
        }
#define SRK(k) { f16s wa, wb, wc, wd; \
        SLOAD4(wa, wb, wc, wd, w0, (7+(k))*256, (7+(k))*256+64, (7+(k))*256+128, (7+(k))*256+192) \
        const float sk = s[k]; \
        FMAROW(xe, sk, wa, wb, wc, wd) }
        REP7(SRK)
#define MUK(k) { f16s wa, wb, wc, wd; \
        SLOAD4(wa, wb, wc, wd, w0, (k)*256, (k)*256+64, (k)*256+128, (k)*256+192) \
        const float mk = mu[k]; \
        FMAROW(xe, mk, wa, wb, wc, wd) }
        REP7(MUK)

        // ---- LayerNorm (two-pass, striped partials: same order as passing kernel) ----
        float p0 = xe[0], p1 = xe[1], p2 = xe[2], p3 = xe[3];
#define SACE(q) p0 += xe[4*(q)+0]; p1 += xe[4*(q)+1]; p2 += xe[4*(q)+2]; p3 += xe[4*(q)+3];
        REP15(SACE)
        float mean = ((p0 + p1) + (p2 + p3)) * (1.0f / HID);

        float v0 = 0.f, v1 = 0.f, v2 = 0.f, v3 = 0.f;
#define VACE(q) { float a0 = xe[4*(q)+0] - mean, a1 = xe[4*(q)+1] - mean; \
        float a2 = xe[4*(q)+2] - mean, a3 = xe[4*(q)+3] - mean; \
        v0 = fmaf(a0, a0, v0); v1 = fmaf(a1, a1, v1); \
        v2 = fmaf(a2, a2, v2); v3 = fmaf(a3, a3, v3); \
        xe[4*(q)+0] = a0; xe[4*(q)+1] = a1; xe[4*(q)+2] = a2; xe[4*(q)+3] = a3; }
        REP16(VACE)
        float var  = ((v0 + v1) + (v2 + v3)) * (1.0f / HID);
        float rstd = 1.0f / sqrtf(var + 1e-6f);

        // ---- scale/shift + GELU (formula identical to passing kernel) ----
#define GELE(e, base, LS, LB) { float g = fmaf(xe[(base)+(e)] * rstd, (LS)[(e)], (LB)[(e)]); \
        float g2 = g * g; float g3 = g2 * g; \
        float z  = -1.5957691216057308f * fmaf(0.044715f, g3, g); \
        float ex = __expf(z); \
        xe[(base)+(e)] = __fdividef(g, 1.0f + ex); }
#define GELG(h) { f16s ls, lb2; \
        SLOAD2P(ls, lb2, lns, lnb, (h)*64, (h)*64) \
        AP16(GELE, 16*(h), ls, lb2) }
        REP4(GELG)

        // ---- out matmul [1x64]x[64x7]: flat-ascending == j-ascending per i ----
        float u[SD];
#define IU(i) u[i] = obv[i];
        REP7(IU)
#define OUTE(e, m, W) u[(16*(m)+(e))%7] = fmaf(xe[(16*(m)+(e))/7], (W)[(e)], u[(16*(m)+(e))%7]);
#define OUTG(g) { f16s a0, a1, a2, a3; \
        SLOAD4(a0, a1, a2, a3, ow, (g)*256, (g)*256+64, (g)*256+128, (g)*256+192) \
        AP16(OUTE, 4*(g)+0, a0) AP16(OUTE, 4*(g)+1, a1) \
        AP16(OUTE, 4*(g)+2, a2) AP16(OUTE, 4*(g)+3, a3) }
        REP7(OUTG)

        // ---- L2 normalize ----
        float ss = 0.f;
#define SSQ(i) ss = fmaf(u[i], u[i], ss);
        REP7(SSQ)
        float inv = __fdividef(1.0f, sqrtf(ss) + 1e-8f);

        // ---- damped update + convergence ----
        float dd = 0.f;
#define UPD(i) { float un = u[i] * inv; float mn = 0.5f * mu[i] + 0.5f * un; \
        float d = mn - mu[i]; dd = fmaf(d, d, dd); mu[i] = mn; }
        REP7(UPD)
        if (sqrtf(dd) < 1e-4f) conv = 1.0f;
    }

#define ST(i) out_mu[(size_t)row * SD + (i)] = mu[i];
    REP7(ST)
    out_cv[row] = conv;
}

extern "C" void kernel_launch(void* const* d_in, const int* in_sizes, int n_in,
                              void* d_out, int out_size, void* d_ws, size_t ws_size,
                              hipStream_t stream) {
    const float* s7  = (const float*)d_in[0];
    const float* w0  = (const float*)d_in[1];
    const float* b0  = (const float*)d_in[2];
    const float* lns = (const float*)d_in[3];
    const float* lnb = (const float*)d_in[4];
    const float* ow  = (const float*)d_in[5];
    const float* ob  = (const float*)d_in[6];
    const int Bn = in_sizes[0] / SD;

    float* out_mu = (float*)d_out;
    float* out_cv = out_mu + (size_t)Bn * SD;

    const int block = 256;
    const int grid  = (Bn + block - 1) / block;
    hipLaunchKernelGGL(strange_loop_kernel, dim3(grid), dim3(block), 0, stream,
                       s7, w0, b0, lns, lnb, ow, ob, out_mu, out_cv, Bn);
}